// Round 7
// baseline (266.804 us; speedup 1.0000x reference)
//
#include <hip/hip_runtime.h>
#include <hip/hip_fp16.h>

#define NEG_SLOPE 0.2f
#define ALPHA_FLAG 0.05f

static inline size_t align256(size_t x) { return (x + 255) & ~(size_t)255; }

// ---------- tiny prep: c = relu(climber@W_c + b_c); gb = c@W_f + b_f ----------
__global__ void prep_kernel(const float* __restrict__ climber,
                            const float* __restrict__ W_c, const float* __restrict__ b_c,
                            const float* __restrict__ W_f1, const float* __restrict__ b_f1,
                            const float* __restrict__ W_f2, const float* __restrict__ b_f2,
                            float* __restrict__ gb1, float* __restrict__ gb2) {
    __shared__ float c_sh[64];
    int g = blockIdx.x, t = threadIdx.x;   // block: 128 threads
    if (t < 64) {
        float acc = b_c[t];
#pragma unroll
        for (int k = 0; k < 4; ++k) acc = fmaf(climber[g * 4 + k], W_c[k * 64 + t], acc);
        c_sh[t] = fmaxf(acc, 0.f);
    }
    __syncthreads();
    float a1 = b_f1[t], a2 = b_f2[t];
#pragma unroll 8
    for (int h = 0; h < 64; ++h) {
        float cv = c_sh[h];
        a1 = fmaf(cv, W_f1[h * 128 + t], a1);
        a2 = fmaf(cv, W_f2[h * 128 + t], a2);
    }
    gb1[g * 128 + t] = a1;
    gb2[g * 128 + t] = a2;
}

// ---------- CSR build ----------
__global__ void init_counts_kernel(int* __restrict__ counts, int N) {
    int i = blockIdx.x * blockDim.x + threadIdx.x;
    if (i < N) counts[i] = 1;   // self-loop
}

__global__ void hist_kernel(const int* __restrict__ dst, int E, int* __restrict__ counts) {
    int i = blockIdx.x * blockDim.x + threadIdx.x;
    if (i < E) atomicAdd(&counts[dst[i]], 1);
}

// ---------- multi-block scan: 49 blocks x 1024 elems ----------
#define SCAN_CHUNK 1024
__global__ void scan_partial_kernel(const int* __restrict__ counts, int* __restrict__ block_sums, int N) {
    __shared__ int sh[256];
    int b = blockIdx.x, t = threadIdx.x;
    int idx0 = b * SCAN_CHUNK + t * 4;
    int s = 0;
    if (idx0 + 3 < N) {
        int4 v = *(const int4*)&counts[idx0];
        s = v.x + v.y + v.z + v.w;
    } else {
#pragma unroll
        for (int u = 0; u < 4; ++u) if (idx0 + u < N) s += counts[idx0 + u];
    }
    sh[t] = s;
    __syncthreads();
#pragma unroll
    for (int off = 128; off; off >>= 1) {
        if (t < off) sh[t] += sh[t + off];
        __syncthreads();
    }
    if (t == 0) block_sums[b] = sh[0];
}

__global__ void scan_blocksums_kernel(const int* __restrict__ block_sums, int* __restrict__ block_bases,
                                      int nb, int* __restrict__ row_ptr, int N) {
    __shared__ int sh[256];
    int t = threadIdx.x;
    int v = (t < nb) ? block_sums[t] : 0;
    sh[t] = v;
    __syncthreads();
#pragma unroll
    for (int off = 1; off < 256; off <<= 1) {
        int add = (t >= off) ? sh[t - off] : 0;
        __syncthreads();
        sh[t] += add;
        __syncthreads();
    }
    if (t < nb) block_bases[t] = sh[t] - v;     // exclusive
    if (t == nb - 1) row_ptr[N] = sh[t];        // total
}

__global__ void scan_final_kernel(const int* __restrict__ counts, const int* __restrict__ block_bases,
                                  int* __restrict__ row_ptr, int* __restrict__ fill, int N) {
    __shared__ int sh[256];
    int b = blockIdx.x, t = threadIdx.x;
    int idx0 = b * SCAN_CHUNK + t * 4;
    int c[4];
    if (idx0 + 3 < N) {
        int4 v = *(const int4*)&counts[idx0];
        c[0] = v.x; c[1] = v.y; c[2] = v.z; c[3] = v.w;
    } else {
#pragma unroll
        for (int u = 0; u < 4; ++u) c[u] = (idx0 + u < N) ? counts[idx0 + u] : 0;
    }
    int s = c[0] + c[1] + c[2] + c[3];
    sh[t] = s;
    __syncthreads();
#pragma unroll
    for (int off = 1; off < 256; off <<= 1) {
        int add = (t >= off) ? sh[t - off] : 0;
        __syncthreads();
        sh[t] += add;
        __syncthreads();
    }
    int run = block_bases[b] + sh[t] - s;
#pragma unroll
    for (int u = 0; u < 4; ++u) {
        if (idx0 + u < N) {
            row_ptr[idx0 + u] = run;
            fill[idx0 + u] = run;
            run += c[u];
        }
    }
}

__global__ void scatter_kernel(const int* __restrict__ src, const int* __restrict__ dst,
                               int E, int N, int* __restrict__ fill, int* __restrict__ csr_src) {
    int i = blockIdx.x * blockDim.x + threadIdx.x;
    if (i >= E + N) return;
    int s, d;
    if (i < E) { s = src[i]; d = dst[i]; }
    else       { s = i - E; d = s; }
    int pos = atomicAdd(&fill[d], 1);
    csr_src[pos] = s;
}

// ---------- per-layer: xh = x@W_g (fp16 out, [n][c][h] interleaved); scores ----------
// in_mode=1: compute x on the fly from x_all (input transform + FiLM1), layer 1
// in_mode=0: load x from xbuf (layer 2)
#define XH_NB 32
__global__ __launch_bounds__(256, 4) void xh_kernel(
    const float* __restrict__ x, const float* __restrict__ W_g,
    const float* __restrict__ a_src, const float* __restrict__ a_dst,
    __half* __restrict__ xh, float* __restrict__ s_src, float* __restrict__ s_dst,
    int N, int in_mode,
    const float* __restrict__ x_all, const int* __restrict__ batch,
    const float* __restrict__ W_in, const float* __restrict__ b_in,
    const float* __restrict__ gb1) {
    __shared__ float x_sh[XH_NB * 64];   // 8 KB
    __shared__ float win_sh[6 * 64 + 64];
    int t = threadIdx.x;
    int base = blockIdx.x * XH_NB;
    if (in_mode) {
        // stage W_in (384 floats) + b_in (64)
        for (int i = t; i < 448; i += 256)
            win_sh[i] = (i < 384) ? W_in[i] : b_in[i - 384];
        __syncthreads();
        int nd = t >> 3;            // node in tile: 0..31
        int jb = (t & 7) * 8;       // output channel block
        int n = base + nd;
        if (n < N) {
            float4 a = *(const float4*)&x_all[(size_t)n * 8];
            float2 b = *(const float2*)&x_all[(size_t)n * 8 + 4];
            float xa[6] = {a.x, a.y, a.z, a.w, b.x, b.y};
            int g = batch[n];
            const float* gbrow = &gb1[g * 128];
#pragma unroll
            for (int jj = 0; jj < 8; ++jj) {
                int j = jb + jj;
                float acc = win_sh[384 + j];
#pragma unroll
                for (int k = 0; k < 6; ++k) acc = fmaf(xa[k], win_sh[k * 64 + j], acc);
                x_sh[nd * 64 + j] = acc * (1.f + gbrow[j]) + gbrow[64 + j];
            }
        } else {
#pragma unroll
            for (int jj = 0; jj < 8; ++jj) x_sh[nd * 64 + jb + jj] = 0.f;
        }
    } else {
        int nvalid = N - base; if (nvalid > XH_NB) nvalid = XH_NB;
        int nfloats = nvalid * 64;
#pragma unroll
        for (int rep = 0; rep < 2; ++rep) {
            int i = t * 4 + rep * 1024;
            float4 v = (i < nfloats) ? *(const float4*)&x[(size_t)base * 64 + i]
                                     : make_float4(0.f, 0.f, 0.f, 0.f);
            *(float4*)&x_sh[i] = v;
        }
    }
    __syncthreads();
    int c = t & 63;     // channel within head
    int g = t >> 6;     // wave id: handles nodes g*8..g*8+7, both heads
    float acc0[8], acc1[8];
#pragma unroll
    for (int i = 0; i < 8; ++i) { acc0[i] = 0.f; acc1[i] = 0.f; }
    const float* W0 = W_g + c;
    const float* W1 = W_g + 64 + c;
#pragma unroll 2
    for (int k = 0; k < 64; k += 4) {
        float w0[4], w1[4];
#pragma unroll
        for (int u = 0; u < 4; ++u) { w0[u] = W0[(k + u) * 128]; w1[u] = W1[(k + u) * 128]; }
#pragma unroll
        for (int i = 0; i < 8; ++i) {
            float4 xv = *(const float4*)&x_sh[(g * 8 + i) * 64 + k];
            acc0[i] = fmaf(xv.x, w0[0], acc0[i]);
            acc0[i] = fmaf(xv.y, w0[1], acc0[i]);
            acc0[i] = fmaf(xv.z, w0[2], acc0[i]);
            acc0[i] = fmaf(xv.w, w0[3], acc0[i]);
            acc1[i] = fmaf(xv.x, w1[0], acc1[i]);
            acc1[i] = fmaf(xv.y, w1[1], acc1[i]);
            acc1[i] = fmaf(xv.z, w1[2], acc1[i]);
            acc1[i] = fmaf(xv.w, w1[3], acc1[i]);
        }
    }
    float as0 = a_src[c], ad0 = a_dst[c];
    float as1 = a_src[64 + c], ad1 = a_dst[64 + c];
#pragma unroll
    for (int i = 0; i < 8; ++i) {
        int n = base + g * 8 + i;
        float ps0 = acc0[i] * as0, pd0 = acc0[i] * ad0;
        float ps1 = acc1[i] * as1, pd1 = acc1[i] * ad1;
#pragma unroll
        for (int off = 32; off; off >>= 1) {
            ps0 += __shfl_xor(ps0, off); pd0 += __shfl_xor(pd0, off);
            ps1 += __shfl_xor(ps1, off); pd1 += __shfl_xor(pd1, off);
        }
        if (n < N) {
            if (c == 0) {
                s_src[n * 2 + 0] = ps0; s_src[n * 2 + 1] = ps1;
                s_dst[n * 2 + 0] = pd0; s_dst[n * 2 + 1] = pd1;
            }
            __half2 hv = __floats2half2_rn(acc0[i], acc1[i]);
            *(__half2*)&xh[(size_t)n * 128 + c * 2] = hv;
        }
    }
}

// ---------- wave-per-node aggregation ----------
// Gather: 16 lanes x dwordx4 cover one 256B xh row; wave does 4 edges per load.
// lane = (sub = lane>>4, q = lane&15); lane accumulates channels q*4..q*4+3
// (x2 heads interleaved) of edges with group-offset sub. Zero-padded edges
// (p=0, off=0) are exact no-ops. After the loop, shfl_xor(16/32) folds subs,
// LDS transpose restores lane=channel for the epilogue.
// mode 0: +bias, relu, FiLM -> write xout (layer 1)
// mode 1: +bias, relu, then fused classifier + flag head -> write out (layer 2)
__global__ __launch_bounds__(256) void agg_kernel(
    const __half* __restrict__ xh, const float* __restrict__ s_src,
    const float* __restrict__ s_dst, const int* __restrict__ row_ptr,
    const int* __restrict__ csr_src, const float* __restrict__ b_g,
    const int* __restrict__ batch, const float* __restrict__ gb_film,
    float* __restrict__ xout, int N, int mode,
    const float* __restrict__ x_all,
    const float* __restrict__ W_cl1, const float* __restrict__ b_cl1,
    const float* __restrict__ W_cl2, const float* __restrict__ b_cl2,
    const float* __restrict__ W_fh1, const float* __restrict__ b_fh1,
    const float* __restrict__ W_fh2, const float* __restrict__ b_fh2,
    float* __restrict__ out) {
    __shared__ float4 ps_sh[4][64];
    __shared__ float vh_sh[4][128];   // [wave][h*64+c]
    int lane = threadIdx.x & 63;
    int w = threadIdx.x >> 6;
    int n = (blockIdx.x * blockDim.x + threadIdx.x) >> 6;
    if (n >= N) return;
    int beg = row_ptr[n], end = row_ptr[n + 1];
    float2 sd = *(const float2*)&s_dst[n * 2];
    const char* xhb = (const char*)xh;
    int sub = lane >> 4;
    unsigned q16 = (unsigned)(lane & 15) * 16u;
    float acc[8] = {0.f, 0.f, 0.f, 0.f, 0.f, 0.f, 0.f, 0.f};
    float dp0 = 0.f, dp1 = 0.f;
    for (int chunk = beg; chunk < end; chunk += 64) {
        int m = end - chunk; if (m > 64) m = 64;
        float p0 = 0.f, p1 = 0.f; unsigned sb = 0;
        if (lane < m) {
            int s = csr_src[chunk + lane];
            sb = (unsigned)s << 8;   // byte offset of xh row (256 B/row)
            float2 ss = *(const float2*)&s_src[s * 2];
            float e0 = ss.x + sd.x;
            float e1 = ss.y + sd.y;
            e0 = (e0 > 0.f) ? e0 : NEG_SLOPE * e0;
            e1 = (e1 > 0.f) ? e1 : NEG_SLOPE * e1;
            p0 = __expf(e0); p1 = __expf(e1);
        }
        dp0 += p0; dp1 += p1;
        ps_sh[w][lane] = make_float4(p0, p1, __uint_as_float(sb), 0.f);
        int mr = (m + 3) & ~3;
        // wave-coherent LDS exchange (single wave, no barrier needed)
        for (int j = 0; j < mr; j += 4) {
            float4 ps = ps_sh[w][j + sub];                   // broadcast x4
            unsigned voff = __float_as_uint(ps.z) + q16;
            uint4 hv = *(const uint4*)(xhb + voff);          // 4 x half2
            float2 c0 = __half22float2(*(__half2*)&hv.x);
            float2 c1 = __half22float2(*(__half2*)&hv.y);
            float2 c2 = __half22float2(*(__half2*)&hv.z);
            float2 c3 = __half22float2(*(__half2*)&hv.w);
            acc[0] = fmaf(ps.x, c0.x, acc[0]); acc[1] = fmaf(ps.y, c0.y, acc[1]);
            acc[2] = fmaf(ps.x, c1.x, acc[2]); acc[3] = fmaf(ps.y, c1.y, acc[3]);
            acc[4] = fmaf(ps.x, c2.x, acc[4]); acc[5] = fmaf(ps.y, c2.y, acc[5]);
            acc[6] = fmaf(ps.x, c3.x, acc[6]); acc[7] = fmaf(ps.y, c3.y, acc[7]);
        }
    }
    // fold the 4 sub-lanes (bits 4,5 of lane)
#pragma unroll
    for (int u = 0; u < 8; ++u) {
        acc[u] += __shfl_xor(acc[u], 16);
        acc[u] += __shfl_xor(acc[u], 32);
    }
#pragma unroll
    for (int off = 32; off; off >>= 1) {
        dp0 += __shfl_xor(dp0, off);
        dp1 += __shfl_xor(dp1, off);
    }
    // transpose to lane=channel via LDS (wave-coherent)
    if (lane < 16) {
        int q4 = lane * 4;
        vh_sh[w][q4 + 0] = acc[0]; vh_sh[w][q4 + 1] = acc[2];
        vh_sh[w][q4 + 2] = acc[4]; vh_sh[w][q4 + 3] = acc[6];
        vh_sh[w][64 + q4 + 0] = acc[1]; vh_sh[w][64 + q4 + 1] = acc[3];
        vh_sh[w][64 + q4 + 2] = acc[5]; vh_sh[w][64 + q4 + 3] = acc[7];
    }
    float A0 = vh_sh[w][lane];
    float A1 = vh_sh[w][64 + lane];
    float v = 0.5f * (A0 / (dp0 + 1e-16f) + A1 / (dp1 + 1e-16f)) + b_g[lane];
    v = fmaxf(v, 0.f);
    if (mode == 0) {
        int g = batch[n];
        v = v * (1.f + gb_film[g * 128 + lane]) + gb_film[g * 128 + 64 + lane];
        xout[(size_t)n * 64 + lane] = v;
        return;
    }
    // ---- fused classifier: lane j computes h_j = relu(b1_j + sum_k v_k W1[k][j]) ----
    vh_sh[w][lane] = v;   // wave-coherent reuse
    float h = b_cl1[lane];
#pragma unroll 4
    for (int k = 0; k < 64; k += 4) {
        float4 vq = *(const float4*)&vh_sh[w][k];   // uniform broadcast
        h = fmaf(vq.x, W_cl1[(k + 0) * 64 + lane], h);
        h = fmaf(vq.y, W_cl1[(k + 1) * 64 + lane], h);
        h = fmaf(vq.z, W_cl1[(k + 2) * 64 + lane], h);
        h = fmaf(vq.w, W_cl1[(k + 3) * 64 + lane], h);
    }
    h = fmaxf(h, 0.f);
    float4 w2 = *(const float4*)&W_cl2[lane * 4];
    float o0 = h * w2.x, o1 = h * w2.y, o2 = h * w2.z, o3 = h * w2.w;
#pragma unroll
    for (int off = 32; off; off >>= 1) {
        o0 += __shfl_xor(o0, off); o1 += __shfl_xor(o1, off);
        o2 += __shfl_xor(o2, off); o3 += __shfl_xor(o3, off);
    }
    if (lane < 4) {
        // flag head, output channel m = lane
        float f0 = x_all[(size_t)n * 8 + 6], f1 = x_all[(size_t)n * 8 + 7];
        float lf = b_fh2[lane];
#pragma unroll
        for (int m = 0; m < 8; ++m) {
            float fm = fmaxf(fmaf(f0, W_fh1[m], fmaf(f1, W_fh1[8 + m], b_fh1[m])), 0.f);
            lf = fmaf(fm, W_fh2[m * 4 + lane], lf);
        }
        float om = (lane == 0) ? o0 : (lane == 1) ? o1 : (lane == 2) ? o2 : o3;
        out[(size_t)n * 4 + lane] = om + b_cl2[lane] + ALPHA_FLAG * lf;
    }
}

extern "C" void kernel_launch(void* const* d_in, const int* in_sizes, int n_in,
                              void* d_out, int out_size, void* d_ws, size_t ws_size,
                              hipStream_t stream) {
    const float* x_all   = (const float*)d_in[0];
    const float* climber = (const float*)d_in[1];
    const int*   eidx    = (const int*)d_in[2];
    const int*   batch   = (const int*)d_in[3];
    const float* W_in  = (const float*)d_in[4];
    const float* b_in  = (const float*)d_in[5];
    const float* W_c   = (const float*)d_in[6];
    const float* b_c   = (const float*)d_in[7];
    const float* W_f1  = (const float*)d_in[8];
    const float* b_f1  = (const float*)d_in[9];
    const float* W_f2  = (const float*)d_in[10];
    const float* b_f2  = (const float*)d_in[11];
    const float* W_g1  = (const float*)d_in[12];
    const float* a_s1  = (const float*)d_in[13];
    const float* a_d1  = (const float*)d_in[14];
    const float* b_g1  = (const float*)d_in[15];
    const float* W_g2  = (const float*)d_in[16];
    const float* a_s2  = (const float*)d_in[17];
    const float* a_d2  = (const float*)d_in[18];
    const float* b_g2  = (const float*)d_in[19];
    const float* W_cl1 = (const float*)d_in[20];
    const float* b_cl1 = (const float*)d_in[21];
    const float* W_cl2 = (const float*)d_in[22];
    const float* b_cl2 = (const float*)d_in[23];
    const float* W_fh1 = (const float*)d_in[24];
    const float* b_fh1 = (const float*)d_in[25];
    const float* W_fh2 = (const float*)d_in[26];
    const float* b_fh2 = (const float*)d_in[27];
    float* out = (float*)d_out;

    const int N = in_sizes[0] / 8;      // 50000
    const int E = in_sizes[2] / 2;      // 800000
    const int G = in_sizes[1] / 4;      // 128
    const int* src = eidx;
    const int* dst = eidx + E;
    const int NB_SCAN = (N + SCAN_CHUNK - 1) / SCAN_CHUNK;   // 49 (must be <= 256)

    char* ws = (char*)d_ws;
    size_t off = 0;
    auto alloc = [&](size_t bytes) { char* p = ws + off; off += align256(bytes); return p; };
    float*  gb1     = (float*)alloc((size_t)G * 128 * 4);
    float*  gb2     = (float*)alloc((size_t)G * 128 * 4);
    float*  xbuf    = (float*)alloc((size_t)N * 64 * 4);
    __half* xh      = (__half*)alloc((size_t)N * 128 * 2);
    float*  s_src   = (float*)alloc((size_t)N * 2 * 4);
    float*  s_dst   = (float*)alloc((size_t)N * 2 * 4);
    int*    counts  = (int*)alloc((size_t)N * 4);
    int*    fill    = (int*)alloc((size_t)N * 4);
    int*    row_ptr = (int*)alloc((size_t)(N + 1) * 4);
    int*    csr_src = (int*)alloc((size_t)(E + N) * 4);
    int*    bsums   = (int*)alloc((size_t)256 * 4);
    int*    bbases  = (int*)alloc((size_t)256 * 4);
    (void)ws_size;

    // 1. FiLM params
    prep_kernel<<<G, 128, 0, stream>>>(climber, W_c, b_c, W_f1, b_f1, W_f2, b_f2, gb1, gb2);
    // 2. CSR build (shared by both layers)
    init_counts_kernel<<<(N + 255) / 256, 256, 0, stream>>>(counts, N);
    hist_kernel<<<(E + 255) / 256, 256, 0, stream>>>(dst, E, counts);
    scan_partial_kernel<<<NB_SCAN, 256, 0, stream>>>(counts, bsums, N);
    scan_blocksums_kernel<<<1, 256, 0, stream>>>(bsums, bbases, NB_SCAN, row_ptr, N);
    scan_final_kernel<<<NB_SCAN, 256, 0, stream>>>(counts, bbases, row_ptr, fill, N);
    scatter_kernel<<<(E + N + 255) / 256, 256, 0, stream>>>(src, dst, E, N, fill, csr_src);
    // 3. GAT layer 1 (input transform + FiLM1 fused into xh; +relu, +FiLM2 in agg)
    xh_kernel<<<(N + XH_NB - 1) / XH_NB, 256, 0, stream>>>(nullptr, W_g1, a_s1, a_d1, xh,
                                                           s_src, s_dst, N, 1,
                                                           x_all, batch, W_in, b_in, gb1);
    agg_kernel<<<(N * 64 + 255) / 256, 256, 0, stream>>>(xh, s_src, s_dst, row_ptr, csr_src,
                                                         b_g1, batch, gb2, xbuf, N, 0,
                                                         nullptr, nullptr, nullptr, nullptr,
                                                         nullptr, nullptr, nullptr, nullptr,
                                                         nullptr, nullptr);
    // 4. GAT layer 2 (+relu) fused with classifier + flag head
    xh_kernel<<<(N + XH_NB - 1) / XH_NB, 256, 0, stream>>>(xbuf, W_g2, a_s2, a_d2, xh,
                                                           s_src, s_dst, N, 0,
                                                           nullptr, nullptr, nullptr, nullptr, nullptr);
    agg_kernel<<<(N * 64 + 255) / 256, 256, 0, stream>>>(xh, s_src, s_dst, row_ptr, csr_src,
                                                         b_g2, batch, nullptr, nullptr, N, 1,
                                                         x_all, W_cl1, b_cl1, W_cl2, b_cl2,
                                                         W_fh1, b_fh1, W_fh2, b_fh2, out);
}

// Round 8
// 265.950 us; speedup vs baseline: 1.0032x; 1.0032x over previous
//
#include <hip/hip_runtime.h>
#include <hip/hip_fp16.h>

#define NEG_SLOPE 0.2f
#define ALPHA_FLAG 0.05f

typedef _Float16 h2t __attribute__((ext_vector_type(2)));
union h2u { unsigned u; h2t h; __half2 hh; float f; };
static __device__ __forceinline__ h2t u_as_h2(unsigned u) { h2u c; c.u = u; return c.h; }
static __device__ __forceinline__ float h2_as_f(__half2 h) { h2u c; c.hh = h; return c.f; }
static __device__ __forceinline__ h2t f_as_h2(float f) { h2u c; c.f = f; return c.h; }

static inline size_t align256(size_t x) { return (x + 255) & ~(size_t)255; }

// ---------- tiny prep: c = relu(climber@W_c + b_c); gb = c@W_f + b_f ----------
__global__ void prep_kernel(const float* __restrict__ climber,
                            const float* __restrict__ W_c, const float* __restrict__ b_c,
                            const float* __restrict__ W_f1, const float* __restrict__ b_f1,
                            const float* __restrict__ W_f2, const float* __restrict__ b_f2,
                            float* __restrict__ gb1, float* __restrict__ gb2) {
    __shared__ float c_sh[64];
    int g = blockIdx.x, t = threadIdx.x;   // block: 128 threads
    if (t < 64) {
        float acc = b_c[t];
#pragma unroll
        for (int k = 0; k < 4; ++k) acc = fmaf(climber[g * 4 + k], W_c[k * 64 + t], acc);
        c_sh[t] = fmaxf(acc, 0.f);
    }
    __syncthreads();
    float a1 = b_f1[t], a2 = b_f2[t];
#pragma unroll 8
    for (int h = 0; h < 64; ++h) {
        float cv = c_sh[h];
        a1 = fmaf(cv, W_f1[h * 128 + t], a1);
        a2 = fmaf(cv, W_f2[h * 128 + t], a2);
    }
    gb1[g * 128 + t] = a1;
    gb2[g * 128 + t] = a2;
}

// ---------- CSR build ----------
__global__ void init_counts_kernel(int* __restrict__ counts, int N) {
    int i = blockIdx.x * blockDim.x + threadIdx.x;
    if (i < N) counts[i] = 1;   // self-loop
}

__global__ void hist_kernel(const int* __restrict__ dst, int E, int* __restrict__ counts) {
    int i = blockIdx.x * blockDim.x + threadIdx.x;
    if (i < E) atomicAdd(&counts[dst[i]], 1);
}

// ---------- multi-block scan: 49 blocks x 1024 elems ----------
#define SCAN_CHUNK 1024
__global__ void scan_partial_kernel(const int* __restrict__ counts, int* __restrict__ block_sums, int N) {
    __shared__ int sh[256];
    int b = blockIdx.x, t = threadIdx.x;
    int idx0 = b * SCAN_CHUNK + t * 4;
    int s = 0;
    if (idx0 + 3 < N) {
        int4 v = *(const int4*)&counts[idx0];
        s = v.x + v.y + v.z + v.w;
    } else {
#pragma unroll
        for (int u = 0; u < 4; ++u) if (idx0 + u < N) s += counts[idx0 + u];
    }
    sh[t] = s;
    __syncthreads();
#pragma unroll
    for (int off = 128; off; off >>= 1) {
        if (t < off) sh[t] += sh[t + off];
        __syncthreads();
    }
    if (t == 0) block_sums[b] = sh[0];
}

__global__ void scan_blocksums_kernel(const int* __restrict__ block_sums, int* __restrict__ block_bases,
                                      int nb, int* __restrict__ row_ptr, int N) {
    __shared__ int sh[256];
    int t = threadIdx.x;
    int v = (t < nb) ? block_sums[t] : 0;
    sh[t] = v;
    __syncthreads();
#pragma unroll
    for (int off = 1; off < 256; off <<= 1) {
        int add = (t >= off) ? sh[t - off] : 0;
        __syncthreads();
        sh[t] += add;
        __syncthreads();
    }
    if (t < nb) block_bases[t] = sh[t] - v;     // exclusive
    if (t == nb - 1) row_ptr[N] = sh[t];        // total
}

__global__ void scan_final_kernel(const int* __restrict__ counts, const int* __restrict__ block_bases,
                                  int* __restrict__ row_ptr, int* __restrict__ fill, int N) {
    __shared__ int sh[256];
    int b = blockIdx.x, t = threadIdx.x;
    int idx0 = b * SCAN_CHUNK + t * 4;
    int c[4];
    if (idx0 + 3 < N) {
        int4 v = *(const int4*)&counts[idx0];
        c[0] = v.x; c[1] = v.y; c[2] = v.z; c[3] = v.w;
    } else {
#pragma unroll
        for (int u = 0; u < 4; ++u) c[u] = (idx0 + u < N) ? counts[idx0 + u] : 0;
    }
    int s = c[0] + c[1] + c[2] + c[3];
    sh[t] = s;
    __syncthreads();
#pragma unroll
    for (int off = 1; off < 256; off <<= 1) {
        int add = (t >= off) ? sh[t - off] : 0;
        __syncthreads();
        sh[t] += add;
        __syncthreads();
    }
    int run = block_bases[b] + sh[t] - s;
#pragma unroll
    for (int u = 0; u < 4; ++u) {
        if (idx0 + u < N) {
            row_ptr[idx0 + u] = run;
            fill[idx0 + u] = run;
            run += c[u];
        }
    }
}

__global__ void scatter_kernel(const int* __restrict__ src, const int* __restrict__ dst,
                               int E, int N, int* __restrict__ fill, int* __restrict__ csr_src) {
    int i = blockIdx.x * blockDim.x + threadIdx.x;
    if (i >= E + N) return;
    int s, d;
    if (i < E) { s = src[i]; d = dst[i]; }
    else       { s = i - E; d = s; }
    int pos = atomicAdd(&fill[d], 1);
    csr_src[pos] = s;
}

// ---------- per-layer: xh = x@W_g (fp16 out, [n][c][h] interleaved); scores ----------
// in_mode=1: compute x on the fly from x_all (input transform + FiLM1), layer 1
// in_mode=0: load x from xbuf (layer 2)
#define XH_NB 32
__global__ __launch_bounds__(256, 4) void xh_kernel(
    const float* __restrict__ x, const float* __restrict__ W_g,
    const float* __restrict__ a_src, const float* __restrict__ a_dst,
    __half* __restrict__ xh, float* __restrict__ s_src, float* __restrict__ s_dst,
    int N, int in_mode,
    const float* __restrict__ x_all, const int* __restrict__ batch,
    const float* __restrict__ W_in, const float* __restrict__ b_in,
    const float* __restrict__ gb1) {
    __shared__ float x_sh[XH_NB * 64];   // 8 KB
    __shared__ float win_sh[6 * 64 + 64];
    int t = threadIdx.x;
    int base = blockIdx.x * XH_NB;
    if (in_mode) {
        // stage W_in (384 floats) + b_in (64)
        for (int i = t; i < 448; i += 256)
            win_sh[i] = (i < 384) ? W_in[i] : b_in[i - 384];
        __syncthreads();
        int nd = t >> 3;            // node in tile: 0..31
        int jb = (t & 7) * 8;       // output channel block
        int n = base + nd;
        if (n < N) {
            float4 a = *(const float4*)&x_all[(size_t)n * 8];
            float2 b = *(const float2*)&x_all[(size_t)n * 8 + 4];
            float xa[6] = {a.x, a.y, a.z, a.w, b.x, b.y};
            int g = batch[n];
            const float* gbrow = &gb1[g * 128];
#pragma unroll
            for (int jj = 0; jj < 8; ++jj) {
                int j = jb + jj;
                float acc = win_sh[384 + j];
#pragma unroll
                for (int k = 0; k < 6; ++k) acc = fmaf(xa[k], win_sh[k * 64 + j], acc);
                x_sh[nd * 64 + j] = acc * (1.f + gbrow[j]) + gbrow[64 + j];
            }
        } else {
#pragma unroll
            for (int jj = 0; jj < 8; ++jj) x_sh[nd * 64 + jb + jj] = 0.f;
        }
    } else {
        int nvalid = N - base; if (nvalid > XH_NB) nvalid = XH_NB;
        int nfloats = nvalid * 64;
#pragma unroll
        for (int rep = 0; rep < 2; ++rep) {
            int i = t * 4 + rep * 1024;
            float4 v = (i < nfloats) ? *(const float4*)&x[(size_t)base * 64 + i]
                                     : make_float4(0.f, 0.f, 0.f, 0.f);
            *(float4*)&x_sh[i] = v;
        }
    }
    __syncthreads();
    int c = t & 63;     // channel within head
    int g = t >> 6;     // wave id: handles nodes g*8..g*8+7, both heads
    float acc0[8], acc1[8];
#pragma unroll
    for (int i = 0; i < 8; ++i) { acc0[i] = 0.f; acc1[i] = 0.f; }
    const float* W0 = W_g + c;
    const float* W1 = W_g + 64 + c;
#pragma unroll 2
    for (int k = 0; k < 64; k += 4) {
        float w0[4], w1[4];
#pragma unroll
        for (int u = 0; u < 4; ++u) { w0[u] = W0[(k + u) * 128]; w1[u] = W1[(k + u) * 128]; }
#pragma unroll
        for (int i = 0; i < 8; ++i) {
            float4 xv = *(const float4*)&x_sh[(g * 8 + i) * 64 + k];
            acc0[i] = fmaf(xv.x, w0[0], acc0[i]);
            acc0[i] = fmaf(xv.y, w0[1], acc0[i]);
            acc0[i] = fmaf(xv.z, w0[2], acc0[i]);
            acc0[i] = fmaf(xv.w, w0[3], acc0[i]);
            acc1[i] = fmaf(xv.x, w1[0], acc1[i]);
            acc1[i] = fmaf(xv.y, w1[1], acc1[i]);
            acc1[i] = fmaf(xv.z, w1[2], acc1[i]);
            acc1[i] = fmaf(xv.w, w1[3], acc1[i]);
        }
    }
    float as0 = a_src[c], ad0 = a_dst[c];
    float as1 = a_src[64 + c], ad1 = a_dst[64 + c];
#pragma unroll
    for (int i = 0; i < 8; ++i) {
        int n = base + g * 8 + i;
        float ps0 = acc0[i] * as0, pd0 = acc0[i] * ad0;
        float ps1 = acc1[i] * as1, pd1 = acc1[i] * ad1;
#pragma unroll
        for (int off = 32; off; off >>= 1) {
            ps0 += __shfl_xor(ps0, off); pd0 += __shfl_xor(pd0, off);
            ps1 += __shfl_xor(ps1, off); pd1 += __shfl_xor(pd1, off);
        }
        if (n < N) {
            if (c == 0) {
                s_src[n * 2 + 0] = ps0; s_src[n * 2 + 1] = ps1;
                s_dst[n * 2 + 0] = pd0; s_dst[n * 2 + 1] = pd1;
            }
            __half2 hv = __floats2half2_rn(acc0[i], acc1[i]);
            *(__half2*)&xh[(size_t)n * 128 + c * 2] = hv;
        }
    }
}

// dot2 helper: acc += w.h0*x.h0 + w.h1*x.h1 (fp32 accumulate)
static __device__ __forceinline__ float dot2acc(unsigned xbits, h2t w, float acc) {
#if __has_builtin(__builtin_amdgcn_fdot2)
    return __builtin_amdgcn_fdot2(u_as_h2(xbits), w, acc, false);
#else
    h2u cx; cx.u = xbits;
    float2 xf = __half22float2(cx.hh);
    h2u cw; cw.h = w;
    float2 wf = __half22float2(cw.hh);
    return fmaf(xf.x, wf.x, fmaf(xf.y, wf.y, acc));
#endif
}

// ---------- wave-per-node aggregation (dot2, pre-normalized softmax) ----------
// Phase 1 computes dp (softmax denominators); alpha = p/dp packed as half2
// (0.5a0, 0.5a1) per edge + row byte-offset in LDS. Gather: 16 lanes x dwordx4
// per row, 4 edges/group, v_dot2_f32_f16 folds both heads into one fp32 acc.
// Fast path deg<=64 keeps phase-1 results in registers; rare deg>64 recomputes.
// mode 0: +bias, relu, FiLM -> write xout (layer 1)
// mode 1: +bias, relu, then fused classifier + flag head -> write out (layer 2)
__global__ __launch_bounds__(256) void agg_kernel(
    const __half* __restrict__ xh, const float* __restrict__ s_src,
    const float* __restrict__ s_dst, const int* __restrict__ row_ptr,
    const int* __restrict__ csr_src, const float* __restrict__ b_g,
    const int* __restrict__ batch, const float* __restrict__ gb_film,
    float* __restrict__ xout, int N, int mode,
    const float* __restrict__ x_all,
    const float* __restrict__ W_cl1, const float* __restrict__ b_cl1,
    const float* __restrict__ W_cl2, const float* __restrict__ b_cl2,
    const float* __restrict__ W_fh1, const float* __restrict__ b_fh1,
    const float* __restrict__ W_fh2, const float* __restrict__ b_fh2,
    float* __restrict__ out) {
    __shared__ float2 ps_sh[4][64];   // (packed half2 alpha, row byte-offset)
    __shared__ float vh_sh[4][64];
    int lane = threadIdx.x & 63;
    int w = threadIdx.x >> 6;
    int n = (blockIdx.x * blockDim.x + threadIdx.x) >> 6;
    if (n >= N) return;
    int beg = row_ptr[n], end = row_ptr[n + 1];
    int deg = end - beg;
    float2 sd = *(const float2*)&s_dst[n * 2];
    const char* xhb = (const char*)xh;
    int sub = lane >> 4;
    unsigned q16 = (unsigned)(lane & 15) * 16u;
    float acc[4] = {0.f, 0.f, 0.f, 0.f};

    if (deg <= 64) {
        // ---- fast path: single chunk, p/sb live in registers ----
        float p0 = 0.f, p1 = 0.f; unsigned sb = 0;
        if (lane < deg) {
            int s = csr_src[beg + lane];
            sb = (unsigned)s << 8;
            float2 ss = *(const float2*)&s_src[s * 2];
            float e0 = ss.x + sd.x, e1 = ss.y + sd.y;
            e0 = (e0 > 0.f) ? e0 : NEG_SLOPE * e0;
            e1 = (e1 > 0.f) ? e1 : NEG_SLOPE * e1;
            p0 = __expf(e0); p1 = __expf(e1);
        }
        float dp0 = p0, dp1 = p1;
#pragma unroll
        for (int off = 32; off; off >>= 1) {
            dp0 += __shfl_xor(dp0, off);
            dp1 += __shfl_xor(dp1, off);
        }
        float i0 = 0.5f / (dp0 + 1e-16f), i1 = 0.5f / (dp1 + 1e-16f);
        ps_sh[w][lane] = make_float2(h2_as_f(__floats2half2_rn(p0 * i0, p1 * i1)),
                                     __uint_as_float(sb));
        int mr = (deg + 3) & ~3;
        for (int j = 0; j < mr; j += 4) {
            float2 ps = ps_sh[w][j + sub];                   // broadcast x4
            h2t wpk = f_as_h2(ps.x);
            unsigned voff = __float_as_uint(ps.y) + q16;
            uint4 hv = *(const uint4*)(xhb + voff);          // 4 x half2
            acc[0] = dot2acc(hv.x, wpk, acc[0]);
            acc[1] = dot2acc(hv.y, wpk, acc[1]);
            acc[2] = dot2acc(hv.z, wpk, acc[2]);
            acc[3] = dot2acc(hv.w, wpk, acc[3]);
        }
    } else {
        // ---- slow path: chunked two-pass (recompute exp in pass 2) ----
        float dp0 = 0.f, dp1 = 0.f;
        for (int chunk = beg; chunk < end; chunk += 64) {
            int m = end - chunk; if (m > 64) m = 64;
            if (lane < m) {
                int s = csr_src[chunk + lane];
                float2 ss = *(const float2*)&s_src[s * 2];
                float e0 = ss.x + sd.x, e1 = ss.y + sd.y;
                e0 = (e0 > 0.f) ? e0 : NEG_SLOPE * e0;
                e1 = (e1 > 0.f) ? e1 : NEG_SLOPE * e1;
                dp0 += __expf(e0); dp1 += __expf(e1);
            }
        }
#pragma unroll
        for (int off = 32; off; off >>= 1) {
            dp0 += __shfl_xor(dp0, off);
            dp1 += __shfl_xor(dp1, off);
        }
        float i0 = 0.5f / (dp0 + 1e-16f), i1 = 0.5f / (dp1 + 1e-16f);
        for (int chunk = beg; chunk < end; chunk += 64) {
            int m = end - chunk; if (m > 64) m = 64;
            float p0 = 0.f, p1 = 0.f; unsigned sb = 0;
            if (lane < m) {
                int s = csr_src[chunk + lane];
                sb = (unsigned)s << 8;
                float2 ss = *(const float2*)&s_src[s * 2];
                float e0 = ss.x + sd.x, e1 = ss.y + sd.y;
                e0 = (e0 > 0.f) ? e0 : NEG_SLOPE * e0;
                e1 = (e1 > 0.f) ? e1 : NEG_SLOPE * e1;
                p0 = __expf(e0); p1 = __expf(e1);
            }
            ps_sh[w][lane] = make_float2(h2_as_f(__floats2half2_rn(p0 * i0, p1 * i1)),
                                         __uint_as_float(sb));
            int mr = (m + 3) & ~3;
            for (int j = 0; j < mr; j += 4) {
                float2 ps = ps_sh[w][j + sub];
                h2t wpk = f_as_h2(ps.x);
                unsigned voff = __float_as_uint(ps.y) + q16;
                uint4 hv = *(const uint4*)(xhb + voff);
                acc[0] = dot2acc(hv.x, wpk, acc[0]);
                acc[1] = dot2acc(hv.y, wpk, acc[1]);
                acc[2] = dot2acc(hv.z, wpk, acc[2]);
                acc[3] = dot2acc(hv.w, wpk, acc[3]);
            }
        }
    }
    // fold the 4 sub-lanes (bits 4,5 of lane)
#pragma unroll
    for (int u = 0; u < 4; ++u) {
        acc[u] += __shfl_xor(acc[u], 16);
        acc[u] += __shfl_xor(acc[u], 32);
    }
    // transpose to lane=channel via LDS (wave-coherent)
    if (lane < 16) *(float4*)&vh_sh[w][lane * 4] = make_float4(acc[0], acc[1], acc[2], acc[3]);
    float v = vh_sh[w][lane] + b_g[lane];
    v = fmaxf(v, 0.f);
    if (mode == 0) {
        int g = batch[n];
        v = v * (1.f + gb_film[g * 128 + lane]) + gb_film[g * 128 + 64 + lane];
        xout[(size_t)n * 64 + lane] = v;
        return;
    }
    // ---- fused classifier: lane j computes h_j = relu(b1_j + sum_k v_k W1[k][j]) ----
    vh_sh[w][lane] = v;   // wave-coherent reuse
    float h = b_cl1[lane];
#pragma unroll 4
    for (int k = 0; k < 64; k += 4) {
        float4 vq = *(const float4*)&vh_sh[w][k];   // uniform broadcast
        h = fmaf(vq.x, W_cl1[(k + 0) * 64 + lane], h);
        h = fmaf(vq.y, W_cl1[(k + 1) * 64 + lane], h);
        h = fmaf(vq.z, W_cl1[(k + 2) * 64 + lane], h);
        h = fmaf(vq.w, W_cl1[(k + 3) * 64 + lane], h);
    }
    h = fmaxf(h, 0.f);
    float4 w2 = *(const float4*)&W_cl2[lane * 4];
    float o0 = h * w2.x, o1 = h * w2.y, o2 = h * w2.z, o3 = h * w2.w;
#pragma unroll
    for (int off = 32; off; off >>= 1) {
        o0 += __shfl_xor(o0, off); o1 += __shfl_xor(o1, off);
        o2 += __shfl_xor(o2, off); o3 += __shfl_xor(o3, off);
    }
    if (lane < 4) {
        // flag head, output channel m = lane
        float f0 = x_all[(size_t)n * 8 + 6], f1 = x_all[(size_t)n * 8 + 7];
        float lf = b_fh2[lane];
#pragma unroll
        for (int m = 0; m < 8; ++m) {
            float fm = fmaxf(fmaf(f0, W_fh1[m], fmaf(f1, W_fh1[8 + m], b_fh1[m])), 0.f);
            lf = fmaf(fm, W_fh2[m * 4 + lane], lf);
        }
        float om = (lane == 0) ? o0 : (lane == 1) ? o1 : (lane == 2) ? o2 : o3;
        out[(size_t)n * 4 + lane] = om + b_cl2[lane] + ALPHA_FLAG * lf;
    }
}

extern "C" void kernel_launch(void* const* d_in, const int* in_sizes, int n_in,
                              void* d_out, int out_size, void* d_ws, size_t ws_size,
                              hipStream_t stream) {
    const float* x_all   = (const float*)d_in[0];
    const float* climber = (const float*)d_in[1];
    const int*   eidx    = (const int*)d_in[2];
    const int*   batch   = (const int*)d_in[3];
    const float* W_in  = (const float*)d_in[4];
    const float* b_in  = (const float*)d_in[5];
    const float* W_c   = (const float*)d_in[6];
    const float* b_c   = (const float*)d_in[7];
    const float* W_f1  = (const float*)d_in[8];
    const float* b_f1  = (const float*)d_in[9];
    const float* W_f2  = (const float*)d_in[10];
    const float* b_f2  = (const float*)d_in[11];
    const float* W_g1  = (const float*)d_in[12];
    const float* a_s1  = (const float*)d_in[13];
    const float* a_d1  = (const float*)d_in[14];
    const float* b_g1  = (const float*)d_in[15];
    const float* W_g2  = (const float*)d_in[16];
    const float* a_s2  = (const float*)d_in[17];
    const float* a_d2  = (const float*)d_in[18];
    const float* b_g2  = (const float*)d_in[19];
    const float* W_cl1 = (const float*)d_in[20];
    const float* b_cl1 = (const float*)d_in[21];
    const float* W_cl2 = (const float*)d_in[22];
    const float* b_cl2 = (const float*)d_in[23];
    const float* W_fh1 = (const float*)d_in[24];
    const float* b_fh1 = (const float*)d_in[25];
    const float* W_fh2 = (const float*)d_in[26];
    const float* b_fh2 = (const float*)d_in[27];
    float* out = (float*)d_out;

    const int N = in_sizes[0] / 8;      // 50000
    const int E = in_sizes[2] / 2;      // 800000
    const int G = in_sizes[1] / 4;      // 128
    const int* src = eidx;
    const int* dst = eidx + E;
    const int NB_SCAN = (N + SCAN_CHUNK - 1) / SCAN_CHUNK;   // 49 (must be <= 256)

    char* ws = (char*)d_ws;
    size_t off = 0;
    auto alloc = [&](size_t bytes) { char* p = ws + off; off += align256(bytes); return p; };
    float*  gb1     = (float*)alloc((size_t)G * 128 * 4);
    float*  gb2     = (float*)alloc((size_t)G * 128 * 4);
    float*  xbuf    = (float*)alloc((size_t)N * 64 * 4);
    __half* xh      = (__half*)alloc((size_t)N * 128 * 2);
    float*  s_src   = (float*)alloc((size_t)N * 2 * 4);
    float*  s_dst   = (float*)alloc((size_t)N * 2 * 4);
    int*    counts  = (int*)alloc((size_t)N * 4);
    int*    fill    = (int*)alloc((size_t)N * 4);
    int*    row_ptr = (int*)alloc((size_t)(N + 1) * 4);
    int*    csr_src = (int*)alloc((size_t)(E + N) * 4);
    int*    bsums   = (int*)alloc((size_t)256 * 4);
    int*    bbases  = (int*)alloc((size_t)256 * 4);
    (void)ws_size;

    // 1. FiLM params
    prep_kernel<<<G, 128, 0, stream>>>(climber, W_c, b_c, W_f1, b_f1, W_f2, b_f2, gb1, gb2);
    // 2. CSR build (shared by both layers)
    init_counts_kernel<<<(N + 255) / 256, 256, 0, stream>>>(counts, N);
    hist_kernel<<<(E + 255) / 256, 256, 0, stream>>>(dst, E, counts);
    scan_partial_kernel<<<NB_SCAN, 256, 0, stream>>>(counts, bsums, N);
    scan_blocksums_kernel<<<1, 256, 0, stream>>>(bsums, bbases, NB_SCAN, row_ptr, N);
    scan_final_kernel<<<NB_SCAN, 256, 0, stream>>>(counts, bbases, row_ptr, fill, N);
    scatter_kernel<<<(E + N + 255) / 256, 256, 0, stream>>>(src, dst, E, N, fill, csr_src);
    // 3. GAT layer 1 (input transform + FiLM1 fused into xh; +relu, +FiLM2 in agg)
    xh_kernel<<<(N + XH_NB - 1) / XH_NB, 256, 0, stream>>>(nullptr, W_g1, a_s1, a_d1, xh,
                                                           s_src, s_dst, N, 1,
                                                           x_all, batch, W_in, b_in, gb1);
    agg_kernel<<<(N * 64 + 255) / 256, 256, 0, stream>>>(xh, s_src, s_dst, row_ptr, csr_src,
                                                         b_g1, batch, gb2, xbuf, N, 0,
                                                         nullptr, nullptr, nullptr, nullptr,
                                                         nullptr, nullptr, nullptr, nullptr,
                                                         nullptr, nullptr);
    // 4. GAT layer 2 (+relu) fused with classifier + flag head
    xh_kernel<<<(N + XH_NB - 1) / XH_NB, 256, 0, stream>>>(xbuf, W_g2, a_s2, a_d2, xh,
                                                           s_src, s_dst, N, 0,
                                                           nullptr, nullptr, nullptr, nullptr, nullptr);
    agg_kernel<<<(N * 64 + 255) / 256, 256, 0, stream>>>(xh, s_src, s_dst, row_ptr, csr_src,
                                                         b_g2, batch, nullptr, nullptr, N, 1,
                                                         x_all, W_cl1, b_cl1, W_cl2, b_cl2,
                                                         W_fh1, b_fh1, W_fh2, b_fh2, out);
}

// Round 9
// 257.509 us; speedup vs baseline: 1.0361x; 1.0328x over previous
//
#include <hip/hip_runtime.h>
#include <hip/hip_fp16.h>

#define NEG_SLOPE 0.2f
#define ALPHA_FLAG 0.05f

typedef _Float16 h2t __attribute__((ext_vector_type(2)));
union h2u { unsigned u; h2t h; __half2 hh; float f; };
static __device__ __forceinline__ h2t u_as_h2(unsigned u) { h2u c; c.u = u; return c.h; }
static __device__ __forceinline__ float h2_as_f(__half2 h) { h2u c; c.hh = h; return c.f; }
static __device__ __forceinline__ h2t f_as_h2(float f) { h2u c; c.f = f; return c.h; }

static inline size_t align256(size_t x) { return (x + 255) & ~(size_t)255; }

// ---------- tiny prep: c = relu(climber@W_c + b_c); gb = c@W_f + b_f ----------
__global__ void prep_kernel(const float* __restrict__ climber,
                            const float* __restrict__ W_c, const float* __restrict__ b_c,
                            const float* __restrict__ W_f1, const float* __restrict__ b_f1,
                            const float* __restrict__ W_f2, const float* __restrict__ b_f2,
                            float* __restrict__ gb1, float* __restrict__ gb2) {
    __shared__ float c_sh[64];
    int g = blockIdx.x, t = threadIdx.x;   // block: 128 threads
    if (t < 64) {
        float acc = b_c[t];
#pragma unroll
        for (int k = 0; k < 4; ++k) acc = fmaf(climber[g * 4 + k], W_c[k * 64 + t], acc);
        c_sh[t] = fmaxf(acc, 0.f);
    }
    __syncthreads();
    float a1 = b_f1[t], a2 = b_f2[t];
#pragma unroll 8
    for (int h = 0; h < 64; ++h) {
        float cv = c_sh[h];
        a1 = fmaf(cv, W_f1[h * 128 + t], a1);
        a2 = fmaf(cv, W_f2[h * 128 + t], a2);
    }
    gb1[g * 128 + t] = a1;
    gb2[g * 128 + t] = a2;
}

// ---------- CSR build (counts zeroed by hipMemsetAsync; self-loop +1 folded into scans) ----------
__global__ void hist_kernel(const int* __restrict__ dst, int E, int* __restrict__ counts) {
    int i4 = (blockIdx.x * blockDim.x + threadIdx.x) * 4;
    if (i4 + 3 < E) {
        int4 d = *(const int4*)&dst[i4];
        atomicAdd(&counts[d.x], 1);
        atomicAdd(&counts[d.y], 1);
        atomicAdd(&counts[d.z], 1);
        atomicAdd(&counts[d.w], 1);
    } else {
        for (int u = 0; u < 4; ++u)
            if (i4 + u < E) atomicAdd(&counts[dst[i4 + u]], 1);
    }
}

#define SCAN_CHUNK 1024
__global__ void scan_partial_kernel(const int* __restrict__ counts, int* __restrict__ block_sums, int N) {
    __shared__ int sh[256];
    int b = blockIdx.x, t = threadIdx.x;
    int idx0 = b * SCAN_CHUNK + t * 4;
    int s = 0;
    if (idx0 + 3 < N) {
        int4 v = *(const int4*)&counts[idx0];
        s = v.x + v.y + v.z + v.w + 4;           // +1 self-loop each
    } else {
#pragma unroll
        for (int u = 0; u < 4; ++u) if (idx0 + u < N) s += counts[idx0 + u] + 1;
    }
    sh[t] = s;
    __syncthreads();
#pragma unroll
    for (int off = 128; off; off >>= 1) {
        if (t < off) sh[t] += sh[t + off];
        __syncthreads();
    }
    if (t == 0) block_sums[b] = sh[0];
}

// final scan: each block re-scans the (<=64) block sums in one wave, then local scan
__global__ void scan_final_kernel(const int* __restrict__ counts, const int* __restrict__ block_sums,
                                  int nb, int* __restrict__ row_ptr, int* __restrict__ fill, int N) {
    __shared__ int sh[256];
    __shared__ int base_sh;
    int b = blockIdx.x, t = threadIdx.x;
    if (t < 64) {
        int v = (t < nb && t < b) ? block_sums[t] : 0;   // masked: sum of blocks before b
#pragma unroll
        for (int off = 32; off; off >>= 1) v += __shfl_xor(v, off);
        if (t == 0) base_sh = v;
    }
    int idx0 = b * SCAN_CHUNK + t * 4;
    int c[4];
    if (idx0 + 3 < N) {
        int4 v = *(const int4*)&counts[idx0];
        c[0] = v.x + 1; c[1] = v.y + 1; c[2] = v.z + 1; c[3] = v.w + 1;
    } else {
#pragma unroll
        for (int u = 0; u < 4; ++u) c[u] = (idx0 + u < N) ? counts[idx0 + u] + 1 : 0;
    }
    int s = c[0] + c[1] + c[2] + c[3];
    sh[t] = s;
    __syncthreads();
#pragma unroll
    for (int off = 1; off < 256; off <<= 1) {
        int add = (t >= off) ? sh[t - off] : 0;
        __syncthreads();
        sh[t] += add;
        __syncthreads();
    }
    int run = base_sh + sh[t] - s;
#pragma unroll
    for (int u = 0; u < 4; ++u) {
        if (idx0 + u < N) {
            row_ptr[idx0 + u] = run;
            fill[idx0 + u] = run;
            run += c[u];
            if (idx0 + u == N - 1) row_ptr[N] = run;
        }
    }
}

__global__ void scatter_kernel(const int* __restrict__ src, const int* __restrict__ dst,
                               int Eh, int N, int* __restrict__ fill, int* __restrict__ csr_src) {
    int t = blockIdx.x * blockDim.x + threadIdx.x;   // Eh = E/2 (E even)
    if (t < Eh) {
        int2 s2 = *(const int2*)&src[t * 2];
        int2 d2 = *(const int2*)&dst[t * 2];
        int p0 = atomicAdd(&fill[d2.x], 1); csr_src[p0] = s2.x;
        int p1 = atomicAdd(&fill[d2.y], 1); csr_src[p1] = s2.y;
    } else {
        int i = t - Eh;
        if (i < N) { int p = atomicAdd(&fill[i], 1); csr_src[p] = i; }   // self-loop
    }
}

// ---------- per-layer: xh = x@W_g (fp16 out, [n][c][h] interleaved); scores ----------
// in_mode=1: compute x on the fly from x_all (input transform + FiLM1), layer 1
// in_mode=0: load x (fp16) from xbuf (layer 2)
#define XH_NB 32
__global__ __launch_bounds__(256, 4) void xh_kernel(
    const __half* __restrict__ xhalf, const float* __restrict__ W_g,
    const float* __restrict__ a_src, const float* __restrict__ a_dst,
    __half* __restrict__ xh, float* __restrict__ s_src, float* __restrict__ s_dst,
    int N, int in_mode,
    const float* __restrict__ x_all, const int* __restrict__ batch,
    const float* __restrict__ W_in, const float* __restrict__ b_in,
    const float* __restrict__ gb1) {
    __shared__ float x_sh[XH_NB * 64];   // 8 KB
    __shared__ float win_sh[6 * 64 + 64];
    int t = threadIdx.x;
    int base = blockIdx.x * XH_NB;
    if (in_mode) {
        for (int i = t; i < 448; i += 256)
            win_sh[i] = (i < 384) ? W_in[i] : b_in[i - 384];
        __syncthreads();
        int nd = t >> 3;            // node in tile: 0..31
        int jb = (t & 7) * 8;       // output channel block
        int n = base + nd;
        if (n < N) {
            float4 a = *(const float4*)&x_all[(size_t)n * 8];
            float2 b = *(const float2*)&x_all[(size_t)n * 8 + 4];
            float xa[6] = {a.x, a.y, a.z, a.w, b.x, b.y};
            int g = batch[n];
            const float* gbrow = &gb1[g * 128];
#pragma unroll
            for (int jj = 0; jj < 8; ++jj) {
                int j = jb + jj;
                float acc = win_sh[384 + j];
#pragma unroll
                for (int k = 0; k < 6; ++k) acc = fmaf(xa[k], win_sh[k * 64 + j], acc);
                x_sh[nd * 64 + j] = acc * (1.f + gbrow[j]) + gbrow[64 + j];
            }
        } else {
#pragma unroll
            for (int jj = 0; jj < 8; ++jj) x_sh[nd * 64 + jb + jj] = 0.f;
        }
    } else {
        int nvalid = N - base; if (nvalid > XH_NB) nvalid = XH_NB;
        int nhalves = nvalid * 64;   // multiple of 64; t*8 either fully in or out
        int idx = t * 8;
        uint4 raw = make_uint4(0, 0, 0, 0);
        if (idx < nhalves) raw = *(const uint4*)&xhalf[(size_t)base * 64 + idx];
        float2 f0 = __half22float2(*(__half2*)&raw.x);
        float2 f1 = __half22float2(*(__half2*)&raw.y);
        float2 f2 = __half22float2(*(__half2*)&raw.z);
        float2 f3 = __half22float2(*(__half2*)&raw.w);
        x_sh[idx + 0] = f0.x; x_sh[idx + 1] = f0.y;
        x_sh[idx + 2] = f1.x; x_sh[idx + 3] = f1.y;
        x_sh[idx + 4] = f2.x; x_sh[idx + 5] = f2.y;
        x_sh[idx + 6] = f3.x; x_sh[idx + 7] = f3.y;
    }
    __syncthreads();
    int c = t & 63;     // channel within head
    int g = t >> 6;     // wave id: handles nodes g*8..g*8+7, both heads
    float acc0[8], acc1[8];
#pragma unroll
    for (int i = 0; i < 8; ++i) { acc0[i] = 0.f; acc1[i] = 0.f; }
    const float* W0 = W_g + c;
    const float* W1 = W_g + 64 + c;
#pragma unroll 2
    for (int k = 0; k < 64; k += 4) {
        float w0[4], w1[4];
#pragma unroll
        for (int u = 0; u < 4; ++u) { w0[u] = W0[(k + u) * 128]; w1[u] = W1[(k + u) * 128]; }
#pragma unroll
        for (int i = 0; i < 8; ++i) {
            float4 xv = *(const float4*)&x_sh[(g * 8 + i) * 64 + k];
            acc0[i] = fmaf(xv.x, w0[0], acc0[i]);
            acc0[i] = fmaf(xv.y, w0[1], acc0[i]);
            acc0[i] = fmaf(xv.z, w0[2], acc0[i]);
            acc0[i] = fmaf(xv.w, w0[3], acc0[i]);
            acc1[i] = fmaf(xv.x, w1[0], acc1[i]);
            acc1[i] = fmaf(xv.y, w1[1], acc1[i]);
            acc1[i] = fmaf(xv.z, w1[2], acc1[i]);
            acc1[i] = fmaf(xv.w, w1[3], acc1[i]);
        }
    }
    float as0 = a_src[c], ad0 = a_dst[c];
    float as1 = a_src[64 + c], ad1 = a_dst[64 + c];
#pragma unroll
    for (int i = 0; i < 8; ++i) {
        int n = base + g * 8 + i;
        float ps0 = acc0[i] * as0, pd0 = acc0[i] * ad0;
        float ps1 = acc1[i] * as1, pd1 = acc1[i] * ad1;
#pragma unroll
        for (int off = 32; off; off >>= 1) {
            ps0 += __shfl_xor(ps0, off); pd0 += __shfl_xor(pd0, off);
            ps1 += __shfl_xor(ps1, off); pd1 += __shfl_xor(pd1, off);
        }
        if (n < N) {
            if (c == 0) {
                s_src[n * 2 + 0] = ps0; s_src[n * 2 + 1] = ps1;
                s_dst[n * 2 + 0] = pd0; s_dst[n * 2 + 1] = pd1;
            }
            __half2 hv = __floats2half2_rn(acc0[i], acc1[i]);
            *(__half2*)&xh[(size_t)n * 128 + c * 2] = hv;
        }
    }
}

// dot2 helper: acc += w.h0*x.h0 + w.h1*x.h1 (fp32 accumulate)
static __device__ __forceinline__ float dot2acc(unsigned xbits, h2t w, float acc) {
#if __has_builtin(__builtin_amdgcn_fdot2)
    return __builtin_amdgcn_fdot2(u_as_h2(xbits), w, acc, false);
#else
    h2u cx; cx.u = xbits;
    float2 xf = __half22float2(cx.hh);
    h2u cw; cw.h = w;
    float2 wf = __half22float2(cw.hh);
    return fmaf(xf.x, wf.x, fmaf(xf.y, wf.y, acc));
#endif
}

// ---------- wave-per-node aggregation core (dot2, pre-normalized softmax) ----------
template <int MODE>
static __device__ __forceinline__ void agg_impl(
    const __half* __restrict__ xh, const float* __restrict__ s_src,
    const float* __restrict__ s_dst, const int* __restrict__ row_ptr,
    const int* __restrict__ csr_src, const float* __restrict__ b_g,
    const int* __restrict__ batch, const float* __restrict__ gb_film,
    __half* __restrict__ xout_h, int N,
    const float* __restrict__ x_all,
    const float* __restrict__ W_cl1, const float* __restrict__ b_cl1,
    const float* __restrict__ W_cl2, const float* __restrict__ b_cl2,
    const float* __restrict__ W_fh1, const float* __restrict__ b_fh1,
    const float* __restrict__ W_fh2, const float* __restrict__ b_fh2,
    float* __restrict__ out) {
    __shared__ float2 ps_sh[4][64];   // (packed half2 alpha, row byte-offset)
    __shared__ float vh_sh[4][64];
    int lane = threadIdx.x & 63;
    int w = threadIdx.x >> 6;
    int n = (blockIdx.x * blockDim.x + threadIdx.x) >> 6;
    if (n >= N) return;
    int beg = row_ptr[n], end = row_ptr[n + 1];
    int deg = end - beg;
    float2 sd = *(const float2*)&s_dst[n * 2];
    const char* xhb = (const char*)xh;
    int sub = lane >> 4;
    unsigned q16 = (unsigned)(lane & 15) * 16u;
    float acc[4] = {0.f, 0.f, 0.f, 0.f};

    if (deg <= 64) {
        float p0 = 0.f, p1 = 0.f; unsigned sb = 0;
        if (lane < deg) {
            int s = csr_src[beg + lane];
            sb = (unsigned)s << 8;
            float2 ss = *(const float2*)&s_src[s * 2];
            float e0 = ss.x + sd.x, e1 = ss.y + sd.y;
            e0 = (e0 > 0.f) ? e0 : NEG_SLOPE * e0;
            e1 = (e1 > 0.f) ? e1 : NEG_SLOPE * e1;
            p0 = __expf(e0); p1 = __expf(e1);
        }
        float dp0 = p0, dp1 = p1;
#pragma unroll
        for (int off = 32; off; off >>= 1) {
            dp0 += __shfl_xor(dp0, off);
            dp1 += __shfl_xor(dp1, off);
        }
        float i0 = 0.5f / (dp0 + 1e-16f), i1 = 0.5f / (dp1 + 1e-16f);
        ps_sh[w][lane] = make_float2(h2_as_f(__floats2half2_rn(p0 * i0, p1 * i1)),
                                     __uint_as_float(sb));
        int mr = (deg + 3) & ~3;
        for (int j = 0; j < mr; j += 4) {
            float2 ps = ps_sh[w][j + sub];                   // broadcast x4
            h2t wpk = f_as_h2(ps.x);
            unsigned voff = __float_as_uint(ps.y) + q16;
            uint4 hv = *(const uint4*)(xhb + voff);          // 4 x half2
            acc[0] = dot2acc(hv.x, wpk, acc[0]);
            acc[1] = dot2acc(hv.y, wpk, acc[1]);
            acc[2] = dot2acc(hv.z, wpk, acc[2]);
            acc[3] = dot2acc(hv.w, wpk, acc[3]);
        }
    } else {
        float dp0 = 0.f, dp1 = 0.f;
        for (int chunk = beg; chunk < end; chunk += 64) {
            int m = end - chunk; if (m > 64) m = 64;
            if (lane < m) {
                int s = csr_src[chunk + lane];
                float2 ss = *(const float2*)&s_src[s * 2];
                float e0 = ss.x + sd.x, e1 = ss.y + sd.y;
                e0 = (e0 > 0.f) ? e0 : NEG_SLOPE * e0;
                e1 = (e1 > 0.f) ? e1 : NEG_SLOPE * e1;
                dp0 += __expf(e0); dp1 += __expf(e1);
            }
        }
#pragma unroll
        for (int off = 32; off; off >>= 1) {
            dp0 += __shfl_xor(dp0, off);
            dp1 += __shfl_xor(dp1, off);
        }
        float i0 = 0.5f / (dp0 + 1e-16f), i1 = 0.5f / (dp1 + 1e-16f);
        for (int chunk = beg; chunk < end; chunk += 64) {
            int m = end - chunk; if (m > 64) m = 64;
            float p0 = 0.f, p1 = 0.f; unsigned sb = 0;
            if (lane < m) {
                int s = csr_src[chunk + lane];
                sb = (unsigned)s << 8;
                float2 ss = *(const float2*)&s_src[s * 2];
                float e0 = ss.x + sd.x, e1 = ss.y + sd.y;
                e0 = (e0 > 0.f) ? e0 : NEG_SLOPE * e0;
                e1 = (e1 > 0.f) ? e1 : NEG_SLOPE * e1;
                p0 = __expf(e0); p1 = __expf(e1);
            }
            ps_sh[w][lane] = make_float2(h2_as_f(__floats2half2_rn(p0 * i0, p1 * i1)),
                                         __uint_as_float(sb));
            int mr = (m + 3) & ~3;
            for (int j = 0; j < mr; j += 4) {
                float2 ps = ps_sh[w][j + sub];
                h2t wpk = f_as_h2(ps.x);
                unsigned voff = __float_as_uint(ps.y) + q16;
                uint4 hv = *(const uint4*)(xhb + voff);
                acc[0] = dot2acc(hv.x, wpk, acc[0]);
                acc[1] = dot2acc(hv.y, wpk, acc[1]);
                acc[2] = dot2acc(hv.z, wpk, acc[2]);
                acc[3] = dot2acc(hv.w, wpk, acc[3]);
            }
        }
    }
#pragma unroll
    for (int u = 0; u < 4; ++u) {
        acc[u] += __shfl_xor(acc[u], 16);
        acc[u] += __shfl_xor(acc[u], 32);
    }
    if (lane < 16) *(float4*)&vh_sh[w][lane * 4] = make_float4(acc[0], acc[1], acc[2], acc[3]);
    float v = vh_sh[w][lane] + b_g[lane];
    v = fmaxf(v, 0.f);
    if (MODE == 0) {
        int g = batch[n];
        v = v * (1.f + gb_film[g * 128 + lane]) + gb_film[g * 128 + 64 + lane];
        xout_h[(size_t)n * 64 + lane] = __float2half(v);
        return;
    }
    // ---- fused classifier ----
    vh_sh[w][lane] = v;
    float h = b_cl1[lane];
#pragma unroll 4
    for (int k = 0; k < 64; k += 4) {
        float4 vq = *(const float4*)&vh_sh[w][k];
        h = fmaf(vq.x, W_cl1[(k + 0) * 64 + lane], h);
        h = fmaf(vq.y, W_cl1[(k + 1) * 64 + lane], h);
        h = fmaf(vq.z, W_cl1[(k + 2) * 64 + lane], h);
        h = fmaf(vq.w, W_cl1[(k + 3) * 64 + lane], h);
    }
    h = fmaxf(h, 0.f);
    float4 w2 = *(const float4*)&W_cl2[lane * 4];
    float o0 = h * w2.x, o1 = h * w2.y, o2 = h * w2.z, o3 = h * w2.w;
#pragma unroll
    for (int off = 32; off; off >>= 1) {
        o0 += __shfl_xor(o0, off); o1 += __shfl_xor(o1, off);
        o2 += __shfl_xor(o2, off); o3 += __shfl_xor(o3, off);
    }
    if (lane < 4) {
        float f0 = x_all[(size_t)n * 8 + 6], f1 = x_all[(size_t)n * 8 + 7];
        float lf = b_fh2[lane];
#pragma unroll
        for (int m = 0; m < 8; ++m) {
            float fm = fmaxf(fmaf(f0, W_fh1[m], fmaf(f1, W_fh1[8 + m], b_fh1[m])), 0.f);
            lf = fmaf(fm, W_fh2[m * 4 + lane], lf);
        }
        float om = (lane == 0) ? o0 : (lane == 1) ? o1 : (lane == 2) ? o2 : o3;
        out[(size_t)n * 4 + lane] = om + b_cl2[lane] + ALPHA_FLAG * lf;
    }
}

__global__ __launch_bounds__(256) void agg_film_kernel(
    const __half* xh, const float* s_src, const float* s_dst, const int* row_ptr,
    const int* csr_src, const float* b_g, const int* batch, const float* gb_film,
    __half* xout_h, int N) {
    agg_impl<0>(xh, s_src, s_dst, row_ptr, csr_src, b_g, batch, gb_film, xout_h, N,
                nullptr, nullptr, nullptr, nullptr, nullptr, nullptr, nullptr,
                nullptr, nullptr, nullptr);
}

__global__ __launch_bounds__(256) void agg_cls_kernel(
    const __half* xh, const float* s_src, const float* s_dst, const int* row_ptr,
    const int* csr_src, const float* b_g, int N, const float* x_all,
    const float* W_cl1, const float* b_cl1, const float* W_cl2, const float* b_cl2,
    const float* W_fh1, const float* b_fh1, const float* W_fh2, const float* b_fh2,
    float* out) {
    agg_impl<1>(xh, s_src, s_dst, row_ptr, csr_src, b_g, nullptr, nullptr, nullptr, N,
                x_all, W_cl1, b_cl1, W_cl2, b_cl2, W_fh1, b_fh1, W_fh2, b_fh2, out);
}

extern "C" void kernel_launch(void* const* d_in, const int* in_sizes, int n_in,
                              void* d_out, int out_size, void* d_ws, size_t ws_size,
                              hipStream_t stream) {
    const float* x_all   = (const float*)d_in[0];
    const float* climber = (const float*)d_in[1];
    const int*   eidx    = (const int*)d_in[2];
    const int*   batch   = (const int*)d_in[3];
    const float* W_in  = (const float*)d_in[4];
    const float* b_in  = (const float*)d_in[5];
    const float* W_c   = (const float*)d_in[6];
    const float* b_c   = (const float*)d_in[7];
    const float* W_f1  = (const float*)d_in[8];
    const float* b_f1  = (const float*)d_in[9];
    const float* W_f2  = (const float*)d_in[10];
    const float* b_f2  = (const float*)d_in[11];
    const float* W_g1  = (const float*)d_in[12];
    const float* a_s1  = (const float*)d_in[13];
    const float* a_d1  = (const float*)d_in[14];
    const float* b_g1  = (const float*)d_in[15];
    const float* W_g2  = (const float*)d_in[16];
    const float* a_s2  = (const float*)d_in[17];
    const float* a_d2  = (const float*)d_in[18];
    const float* b_g2  = (const float*)d_in[19];
    const float* W_cl1 = (const float*)d_in[20];
    const float* b_cl1 = (const float*)d_in[21];
    const float* W_cl2 = (const float*)d_in[22];
    const float* b_cl2 = (const float*)d_in[23];
    const float* W_fh1 = (const float*)d_in[24];
    const float* b_fh1 = (const float*)d_in[25];
    const float* W_fh2 = (const float*)d_in[26];
    const float* b_fh2 = (const float*)d_in[27];
    float* out = (float*)d_out;

    const int N = in_sizes[0] / 8;      // 50000
    const int E = in_sizes[2] / 2;      // 800000 (even)
    const int G = in_sizes[1] / 4;      // 128
    const int* src = eidx;
    const int* dst = eidx + E;
    const int NB_SCAN = (N + SCAN_CHUNK - 1) / SCAN_CHUNK;   // 49 (<= 64)

    char* ws = (char*)d_ws;
    size_t off = 0;
    auto alloc = [&](size_t bytes) { char* p = ws + off; off += align256(bytes); return p; };
    float*  gb1     = (float*)alloc((size_t)G * 128 * 4);
    float*  gb2     = (float*)alloc((size_t)G * 128 * 4);
    __half* xbuf    = (__half*)alloc((size_t)N * 64 * 2);
    __half* xh      = (__half*)alloc((size_t)N * 128 * 2);
    float*  s_src   = (float*)alloc((size_t)N * 2 * 4);
    float*  s_dst   = (float*)alloc((size_t)N * 2 * 4);
    int*    counts  = (int*)alloc((size_t)N * 4);
    int*    fill    = (int*)alloc((size_t)N * 4);
    int*    row_ptr = (int*)alloc((size_t)(N + 1) * 4);
    int*    csr_src = (int*)alloc((size_t)(E + N) * 4);
    int*    bsums   = (int*)alloc((size_t)64 * 4);
    (void)ws_size;

    // 1. FiLM params
    prep_kernel<<<G, 128, 0, stream>>>(climber, W_c, b_c, W_f1, b_f1, W_f2, b_f2, gb1, gb2);
    // 2. CSR build (shared by both layers)
    hipMemsetAsync(counts, 0, (size_t)N * 4, stream);
    hist_kernel<<<(E / 4 + 255) / 256, 256, 0, stream>>>(dst, E, counts);
    scan_partial_kernel<<<NB_SCAN, 256, 0, stream>>>(counts, bsums, N);
    scan_final_kernel<<<NB_SCAN, 256, 0, stream>>>(counts, bsums, NB_SCAN, row_ptr, fill, N);
    scatter_kernel<<<(E / 2 + N + 255) / 256, 256, 0, stream>>>(src, dst, E / 2, N, fill, csr_src);
    // 3. GAT layer 1 (input transform + FiLM1 fused into xh; +relu, +FiLM2 in agg)
    xh_kernel<<<(N + XH_NB - 1) / XH_NB, 256, 0, stream>>>(nullptr, W_g1, a_s1, a_d1, xh,
                                                           s_src, s_dst, N, 1,
                                                           x_all, batch, W_in, b_in, gb1);
    agg_film_kernel<<<(N * 64 + 255) / 256, 256, 0, stream>>>(xh, s_src, s_dst, row_ptr, csr_src,
                                                              b_g1, batch, gb2, xbuf, N);
    // 4. GAT layer 2 (+relu) fused with classifier + flag head
    xh_kernel<<<(N + XH_NB - 1) / XH_NB, 256, 0, stream>>>(xbuf, W_g2, a_s2, a_d2, xh,
                                                           s_src, s_dst, N, 0,
                                                           nullptr, nullptr, nullptr, nullptr, nullptr);
    agg_cls_kernel<<<(N * 64 + 255) / 256, 256, 0, stream>>>(xh, s_src, s_dst, row_ptr, csr_src,
                                                             b_g2, N, x_all, W_cl1, b_cl1,
                                                             W_cl2, b_cl2, W_fh1, b_fh1,
                                                             W_fh2, b_fh2, out);
}